// Round 8
// baseline (590.018 us; speedup 1.0000x reference)
//
#include <hip/hip_runtime.h>
#include <cmath>

// EstimatorQNNGen275: conv+sigmoid+mean -> 1-dim attention -> 4-layer tanh MLP
// (3x 512x4096x4096 GEMMs via fp16 MFMA, split-K, dbuf raw-barrier pipeline,
// W pre-converted fp16) -> pairwise-fidelity graph.
//
// R8: dispatch-count reduction 13 -> 8. R0-R7 accounting shows a stable
// ~14us x n_dispatch residual no in-loop change touches. Fusions (all
// role-split or element-aligned, no new cross-block sync in the schedule):
//   - wconv(W2) rides attn_layer1 as extra blocks
//   - wconv(W3)/wconv(W4) ride combine1/combine2 (single wh is race-free:
//     stream serializes; each wconv sits between the gemm reading old W and
//     the gemm reading new W)
//   - fid fused into combine3 (element-aligned, v4 = just-computed out);
//     finalize in the last-finisher block via threadfence + atomic ticket;
//     D read back with atomic fetch-add-0 (XCD-coherent).
// GEMM body is R7's proven structure, untouched.
//
// ws layout (bytes):
//   [0,2048)     c_buf (512 f32)
//   [4096,4768)  D (10 dots stride-16 f32 + ticket counter at D[160])
//   [8192,...)   act1,act2,act3 (f32 8MB) ; a1h,a2h,a3h (fp16 4MB)
//                ; wh (fp16 32MB) ; part (Z x 8MB split-K partials)

#define NEL (512 * 4096)

typedef float  floatx4 __attribute__((ext_vector_type(4)));
typedef _Float16 halfx8 __attribute__((ext_vector_type(8)));
typedef _Float16 halfx4 __attribute__((ext_vector_type(4)));

#define BM 128
#define BN 128
#define BK 32
#define LDK 40  // padded leading dim (halfs), R1-proven

// ---------------- conv + sigmoid + mean (float4) + D/ticket zeroing ---------
__global__ __launch_bounds__(256) void conv_mean_kernel(
    const float* __restrict__ x, const float* __restrict__ cw,
    const float* __restrict__ cb, float* __restrict__ c_out,
    float* __restrict__ D)
{
  __shared__ float sbuf[4];
  const int b = blockIdx.x;
  if (b == 0 && threadIdx.x < 168) D[threadIdx.x] = 0.f;  // dots + ticket
  const float w00 = cw[0], w01 = cw[1], w10 = cw[2], w11 = cw[3];
  const float bias = cb[0];
  const float* xb = x + (size_t)b * 128 * 128;
  float acc = 0.f;
  for (int t = threadIdx.x; t < 127 * 32; t += 256) {
    const int i  = t >> 5;
    const int j0 = (t & 31) << 2;
    const float* pr0 = xb + i * 128 + j0;
    const float* pr1 = pr0 + 128;
    const float4 a4 = *reinterpret_cast<const float4*>(pr0);
    const float  a5 = pr0[4];
    const float4 b4 = *reinterpret_cast<const float4*>(pr1);
    const float  b5 = pr1[4];
    const float a[5] = {a4.x, a4.y, a4.z, a4.w, a5};
    const float bb[5] = {b4.x, b4.y, b4.z, b4.w, b5};
    #pragma unroll
    for (int m = 0; m < 4; ++m) {
      if (j0 + m < 127) {
        float v = w00 * a[m] + w01 * a[m + 1] + w10 * bb[m] + w11 * bb[m + 1] + bias;
        acc += 1.0f / (1.0f + __expf(-v));
      }
    }
  }
  #pragma unroll
  for (int off = 32; off > 0; off >>= 1) acc += __shfl_down(acc, off, 64);
  const int lane = threadIdx.x & 63, wv = threadIdx.x >> 6;
  if (lane == 0) sbuf[wv] = acc;
  __syncthreads();
  if (threadIdx.x == 0)
    c_out[b] = (sbuf[0] + sbuf[1] + sbuf[2] + sbuf[3]) * (1.0f / 16129.0f);
}

// ---- fp32 -> fp16 streaming conversion body (RNE), grid-stride over n8 -----
__device__ __forceinline__ void wconv_body(const float* __restrict__ w,
                                           _Float16* __restrict__ wh,
                                           int start, int stride)
{
  const int n8 = 4096 * 4096 / 8;
  const float4* w4 = (const float4*)w;
  for (int i = start; i < n8; i += stride) {
    const float4 a = w4[2 * i];
    const float4 b = w4[2 * i + 1];
    halfx8 h = { (_Float16)a.x, (_Float16)a.y, (_Float16)a.z, (_Float16)a.w,
                 (_Float16)b.x, (_Float16)b.y, (_Float16)b.z, (_Float16)b.w };
    ((halfx8*)wh)[i] = h;
  }
}

// ---- attention (wave 0, exact) + layer 1 fused; extra blocks do wconv ------
__global__ __launch_bounds__(256) void attn_l1w_kernel(
    const float* __restrict__ c, const float* __restrict__ rot,
    const float* __restrict__ ent, const float* __restrict__ W1,
    const float* __restrict__ b1, float* __restrict__ act1,
    _Float16* __restrict__ a1h,
    const float* __restrict__ wsrc, _Float16* __restrict__ wdst)
{
  if (blockIdx.x >= 512) {  // wconv role: 2048 blocks
    wconv_body(wsrc, wdst, (blockIdx.x - 512) * 256 + threadIdx.x, 2048 * 256);
    return;
  }
  __shared__ float sattn;
  const int i = blockIdx.x;
  if (threadIdx.x < 64) {
    const int lane = threadIdx.x;
    const float t = rot[0] * ent[0] * c[i];
    float vals[8], cj[8];
    float mx = -1e30f;
    #pragma unroll
    for (int u = 0; u < 8; ++u) {
      float cv = c[lane + u * 64];
      cj[u] = cv;
      vals[u] = t * cv;
      mx = fmaxf(mx, vals[u]);
    }
    #pragma unroll
    for (int off = 32; off > 0; off >>= 1) mx = fmaxf(mx, __shfl_down(mx, off, 64));
    mx = __shfl(mx, 0, 64);
    float se = 0.f, sw = 0.f;
    #pragma unroll
    for (int u = 0; u < 8; ++u) {
      float e = __expf(vals[u] - mx);
      se += e;
      sw += e * cj[u];
    }
    #pragma unroll
    for (int off = 32; off > 0; off >>= 1) {
      se += __shfl_down(se, off, 64);
      sw += __shfl_down(sw, off, 64);
    }
    if (lane == 0) sattn = sw / se;
  }
  __syncthreads();
  const float av = sattn;
  #pragma unroll
  for (int k = 0; k < 16; ++k) {
    const int o = k * 256 + threadIdx.x;
    const float v = tanhf(av * W1[o] + b1[o]);
    act1[(size_t)i * 4096 + o] = v;
    a1h[(size_t)i * 4096 + o] = (_Float16)v;
  }
}

// ---------------- fp16-MFMA GEMM (R7 structure, both operands fp16) ---------
__global__ __launch_bounds__(256, 4) void gemm_kernel(
    const _Float16* __restrict__ A16, const _Float16* __restrict__ W16,
    float* __restrict__ part)
{
  __shared__ _Float16 As[2][BM][LDK];
  __shared__ _Float16 Ws[2][BN][LDK];
  const int K = 4096, N = 4096;
  const int tid  = threadIdx.x;
  const int lane = tid & 63;
  const int wave = tid >> 6;
  const int wm = (wave >> 1) * 64;
  const int wn = (wave & 1) * 64;
  const int q  = lane >> 4;
  const int ml = lane & 15;
  const int tileM = blockIdx.y * BM;
  const int tileN = blockIdx.x * BN;
  const int Kslice = K / gridDim.z;
  const int kbeg = blockIdx.z * Kslice;
  const int kend = kbeg + Kslice;
  float* Cb = part + (size_t)blockIdx.z * NEL;

  floatx4 acc[4][4] = {};

  const int r0  = tid >> 2;
  const int cc0 = (tid & 3) << 3;

  halfx8 pa[2], pw[2];
  auto load_tile = [&](int k0) {
    #pragma unroll
    for (int u = 0; u < 2; ++u) {
      pa[u] = *reinterpret_cast<const halfx8*>(
          A16 + (size_t)(tileM + r0 + u * 64) * K + k0 + cc0);
      pw[u] = *reinterpret_cast<const halfx8*>(
          W16 + (size_t)(tileN + r0 + u * 64) * K + k0 + cc0);
    }
  };
  auto store_tile = [&](int buf) {
    #pragma unroll
    for (int u = 0; u < 2; ++u) {
      *reinterpret_cast<halfx8*>(&As[buf][r0 + u * 64][cc0]) = pa[u];
      *reinterpret_cast<halfx8*>(&Ws[buf][r0 + u * 64][cc0]) = pw[u];
    }
  };

  load_tile(kbeg);
  store_tile(0);
  int cur = 0;

  for (int k0 = kbeg; k0 < kend; k0 += BK) {
    const bool more = (k0 + BK < kend);
    if (more) load_tile(k0 + BK);   // stays in flight across the raw barrier

    asm volatile("s_waitcnt lgkmcnt(0)" ::: "memory");
    __builtin_amdgcn_s_barrier();

    halfx8 af[4], bf[4];
    #pragma unroll
    for (int i = 0; i < 4; ++i)
      af[i] = *reinterpret_cast<const halfx8*>(&As[cur][wm + i * 16 + ml][q * 8]);
    #pragma unroll
    for (int j = 0; j < 4; ++j)
      bf[j] = *reinterpret_cast<const halfx8*>(&Ws[cur][wn + j * 16 + ml][q * 8]);

    #pragma unroll
    for (int i = 0; i < 4; ++i)
      #pragma unroll
      for (int j = 0; j < 4; ++j)
        acc[i][j] = __builtin_amdgcn_mfma_f32_16x16x32_f16(af[i], bf[j], acc[i][j], 0, 0, 0);

    if (more) store_tile(cur ^ 1);  // compiler's vmcnt wait lands here
    cur ^= 1;
  }

  // C/D layout: col=lane&15, row=(lane>>4)*4+reg
  #pragma unroll
  for (int i = 0; i < 4; ++i) {
    const int row0 = tileM + wm + i * 16 + q * 4;
    #pragma unroll
    for (int j = 0; j < 4; ++j) {
      const int col = tileN + wn + j * 16 + ml;
      #pragma unroll
      for (int r = 0; r < 4; ++r)
        Cb[(size_t)(row0 + r) * N + col] = acc[i][j][r];
    }
  }
}

// -- split-K combine + bias + tanh + fp16 copy; extra blocks wconv next W ----
template<int S>
__global__ __launch_bounds__(256) void combine_w_kernel(
    const float* __restrict__ part, const float* __restrict__ bias,
    float* __restrict__ outp, _Float16* __restrict__ houtp,
    const float* __restrict__ wsrc, _Float16* __restrict__ wdst)
{
  if (blockIdx.x >= 2048) {  // wconv role: 2048 blocks
    wconv_body(wsrc, wdst, (blockIdx.x - 2048) * 256 + threadIdx.x, 2048 * 256);
    return;
  }
  const int i4 = blockIdx.x * 256 + threadIdx.x;  // < NEL/4
  const floatx4* p4 = (const floatx4*)part;
  floatx4 s = p4[i4];
  #pragma unroll
  for (int z = 1; z < S; ++z) s += p4[(size_t)z * (NEL / 4) + i4];
  const floatx4 bv = ((const floatx4*)bias)[i4 & 1023];
  floatx4 o;
  #pragma unroll
  for (int r = 0; r < 4; ++r) o[r] = tanhf(s[r] + bv[r]);
  ((floatx4*)outp)[i4] = o;
  halfx4 h = { (_Float16)o[0], (_Float16)o[1], (_Float16)o[2], (_Float16)o[3] };
  ((halfx4*)houtp)[i4] = h;
}

// -- final combine + fid partial dots + last-block finalize (atomic ticket) --
template<int S>
__global__ __launch_bounds__(256) void combine_fid_kernel(
    const float* __restrict__ part, const float* __restrict__ bias,
    float* __restrict__ outp,
    const float* __restrict__ a1, const float* __restrict__ a2,
    const float* __restrict__ a3, float* __restrict__ D,
    float* __restrict__ wout)
{
  __shared__ float sred[4][10];
  __shared__ int slast;
  const int i4 = blockIdx.x * 256 + threadIdx.x;  // < NEL/4
  const floatx4* p4 = (const floatx4*)part;
  floatx4 s = p4[i4];
  #pragma unroll
  for (int z = 1; z < S; ++z) s += p4[(size_t)z * (NEL / 4) + i4];
  const floatx4 bv = ((const floatx4*)bias)[i4 & 1023];
  floatx4 o;
  #pragma unroll
  for (int r = 0; r < 4; ++r) o[r] = tanhf(s[r] + bv[r]);
  ((floatx4*)outp)[i4] = o;

  // fid partial products for this block's element range (v4 == o)
  const floatx4 v1 = ((const floatx4*)a1)[i4];
  const floatx4 v2 = ((const floatx4*)a2)[i4];
  const floatx4 v3 = ((const floatx4*)a3)[i4];
  float sc[10] = {0, 0, 0, 0, 0, 0, 0, 0, 0, 0};
  #pragma unroll
  for (int r = 0; r < 4; ++r) {
    sc[0] += v1[r] * v1[r]; sc[1] += v1[r] * v2[r]; sc[2] += v1[r] * v3[r];
    sc[3] += v1[r] * o[r];  sc[4] += v2[r] * v2[r]; sc[5] += v2[r] * v3[r];
    sc[6] += v2[r] * o[r];  sc[7] += v3[r] * v3[r]; sc[8] += v3[r] * o[r];
    sc[9] += o[r] * o[r];
  }
  const int lane = threadIdx.x & 63, wv = threadIdx.x >> 6;
  #pragma unroll
  for (int p = 0; p < 10; ++p) {
    float v = sc[p];
    #pragma unroll
    for (int off = 32; off > 0; off >>= 1) v += __shfl_down(v, off, 64);
    if (lane == 0) sred[wv][p] = v;
  }
  __syncthreads();
  if (threadIdx.x < 10) {
    float v = sred[0][threadIdx.x] + sred[1][threadIdx.x] +
              sred[2][threadIdx.x] + sred[3][threadIdx.x];
    atomicAdd(&D[threadIdx.x * 16], v);
  }
  // ticket: adds (device-scope atomics) made visible, then count this block.
  __threadfence();
  __syncthreads();
  if (threadIdx.x == 0)
    slast = (atomicAdd((int*)&D[160], 1) == (int)gridDim.x - 1) ? 1 : 0;
  __syncthreads();
  if (slast && threadIdx.x < 16) {
    // read D through the same coherent atomic path (fetch-add 0)
    const int i = threadIdx.x;
    const int p = i >> 2, qq = i & 3;
    const int a = p < qq ? p : qq;
    const int b = p < qq ? qq : p;
    const int base[4] = {0, 4, 7, 9};
    const float dpq = atomicAdd(&D[(base[a] + (b - a)) * 16], 0.0f);
    const float npv = sqrtf(atomicAdd(&D[base[p] * 16], 0.0f)) + 1e-12f;
    const float nqv = sqrtf(atomicAdd(&D[base[qq] * 16], 0.0f)) + 1e-12f;
    const float ch = dpq / (npv * nqv);
    const float fid = ch * ch;
    wout[i] = (fid >= 0.8f && p != qq) ? 1.0f : 0.0f;
  }
}

extern "C" void kernel_launch(void* const* d_in, const int* in_sizes, int n_in,
                              void* d_out, int out_size, void* d_ws, size_t ws_size,
                              hipStream_t stream)
{
  const float* x   = (const float*)d_in[0];
  const float* cw  = (const float*)d_in[1];
  const float* cb  = (const float*)d_in[2];
  const float* rot = (const float*)d_in[3];
  const float* ent = (const float*)d_in[4];
  const float* W1  = (const float*)d_in[5];
  const float* b1  = (const float*)d_in[6];
  const float* W2  = (const float*)d_in[7];
  const float* b2  = (const float*)d_in[8];
  const float* W3  = (const float*)d_in[9];
  const float* b3  = (const float*)d_in[10];
  const float* W4  = (const float*)d_in[11];
  const float* b4  = (const float*)d_in[12];
  float* out = (float*)d_out;

  char*  ws    = (char*)d_ws;
  float* c_buf = (float*)(ws + 0);
  float* D     = (float*)(ws + 4096);
  float* act1  = (float*)(ws + 8192);
  float* act2  = act1 + NEL;
  float* act3  = act2 + NEL;
  _Float16* a1h = (_Float16*)(act3 + NEL);
  _Float16* a2h = a1h + NEL;
  _Float16* a3h = a2h + NEL;
  _Float16* wh  = a3h + NEL;                          // 4096x4096 fp16 = 32MB
  float* part  = (float*)(wh + (size_t)4096 * 4096);  // Z x NEL fp32 partials
  float* wout  = out + NEL;

  const size_t base_need = 8192 + (size_t)3 * NEL * 4 + (size_t)3 * NEL * 2
                         + (size_t)4096 * 4096 * 2;           // ~68 MB
  const bool sk8 = ws_size >= base_need + (size_t)8 * NEL * 4;  // ~132 MB

  conv_mean_kernel<<<512, 256, 0, stream>>>(x, cw, cb, c_buf, D);
  attn_l1w_kernel<<<2560, 256, 0, stream>>>(c_buf, rot, ent, W1, b1,
                                            act1, a1h, W2, wh);

  if (sk8) {
    dim3 g(32, 4, 8);  // 1024 blocks, 4 blocks/CU, single generation
    gemm_kernel<<<g, 256, 0, stream>>>(a1h, wh, part);
    combine_w_kernel<8><<<4096, 256, 0, stream>>>(part, b2, act2, a2h, W3, wh);
    gemm_kernel<<<g, 256, 0, stream>>>(a2h, wh, part);
    combine_w_kernel<8><<<4096, 256, 0, stream>>>(part, b3, act3, a3h, W4, wh);
    gemm_kernel<<<g, 256, 0, stream>>>(a3h, wh, part);
    combine_fid_kernel<8><<<2048, 256, 0, stream>>>(part, b4, out,
                                                    act1, act2, act3, D, wout);
  } else {
    dim3 g(32, 4, 4);  // 512 blocks; ~100MB footprint (R7-proven fallback)
    gemm_kernel<<<g, 256, 0, stream>>>(a1h, wh, part);
    combine_w_kernel<4><<<4096, 256, 0, stream>>>(part, b2, act2, a2h, W3, wh);
    gemm_kernel<<<g, 256, 0, stream>>>(a2h, wh, part);
    combine_w_kernel<4><<<4096, 256, 0, stream>>>(part, b3, act3, a3h, W4, wh);
    gemm_kernel<<<g, 256, 0, stream>>>(a3h, wh, part);
    combine_fid_kernel<4><<<2048, 256, 0, stream>>>(part, b4, out,
                                                    act1, act2, act3, D, wout);
  }
}

// Round 9
// 385.657 us; speedup vs baseline: 1.5299x; 1.5299x over previous
//
#include <hip/hip_runtime.h>
#include <cmath>

// EstimatorQNNGen275: conv+sigmoid+mean -> 1-dim attention -> 4-layer tanh MLP
// (3x 512x4096x4096 GEMMs via fp16 MFMA, split-K, dbuf raw-barrier pipeline,
// W pre-converted fp16) -> pairwise-fidelity graph.
//
// R9: revert R8's combine_fid fusion (per-block __threadfence = device-scope
// fence on non-coherent XCD L2s -> L2 writeback storm, 185us). Back to the
// proven combine3 + 256-block fid_dots + finalize. Keep the neutral fusions:
// wconv(W2) rides attn_layer1, wconv(W3/W4) ride combine1/combine2 (single
// wh race-free: stream serializes; each wconv sits between the gemm reading
// old W and the gemm reading new W). GEMM body is R7's proven structure.
// Ledger note: dur_us ~= ~220us our kernels + ~185us harness workspace fills
// (five 256MiB fillBufferAligned @ ~40us in every profile) -- fixed overhead.
//
// ws layout (bytes):
//   [0,2048)     c_buf (512 f32)
//   [4096,4736)  D (10 dots stride-16 f32)
//   [8192,...)   act1,act2,act3 (f32 8MB) ; a1h,a2h,a3h (fp16 4MB)
//                ; wh (fp16 32MB) ; part (Z x 8MB split-K partials)

#define NEL (512 * 4096)

typedef float  floatx4 __attribute__((ext_vector_type(4)));
typedef _Float16 halfx8 __attribute__((ext_vector_type(8)));
typedef _Float16 halfx4 __attribute__((ext_vector_type(4)));

#define BM 128
#define BN 128
#define BK 32
#define LDK 40  // padded leading dim (halfs), R1-proven

// ---------------- conv + sigmoid + mean (float4) + D zeroing ----------------
__global__ __launch_bounds__(256) void conv_mean_kernel(
    const float* __restrict__ x, const float* __restrict__ cw,
    const float* __restrict__ cb, float* __restrict__ c_out,
    float* __restrict__ D)
{
  __shared__ float sbuf[4];
  const int b = blockIdx.x;
  if (b == 0 && threadIdx.x < 160) D[threadIdx.x] = 0.f;
  const float w00 = cw[0], w01 = cw[1], w10 = cw[2], w11 = cw[3];
  const float bias = cb[0];
  const float* xb = x + (size_t)b * 128 * 128;
  float acc = 0.f;
  for (int t = threadIdx.x; t < 127 * 32; t += 256) {
    const int i  = t >> 5;
    const int j0 = (t & 31) << 2;
    const float* pr0 = xb + i * 128 + j0;
    const float* pr1 = pr0 + 128;
    const float4 a4 = *reinterpret_cast<const float4*>(pr0);
    const float  a5 = pr0[4];
    const float4 b4 = *reinterpret_cast<const float4*>(pr1);
    const float  b5 = pr1[4];
    const float a[5] = {a4.x, a4.y, a4.z, a4.w, a5};
    const float bb[5] = {b4.x, b4.y, b4.z, b4.w, b5};
    #pragma unroll
    for (int m = 0; m < 4; ++m) {
      if (j0 + m < 127) {
        float v = w00 * a[m] + w01 * a[m + 1] + w10 * bb[m] + w11 * bb[m + 1] + bias;
        acc += 1.0f / (1.0f + __expf(-v));
      }
    }
  }
  #pragma unroll
  for (int off = 32; off > 0; off >>= 1) acc += __shfl_down(acc, off, 64);
  const int lane = threadIdx.x & 63, wv = threadIdx.x >> 6;
  if (lane == 0) sbuf[wv] = acc;
  __syncthreads();
  if (threadIdx.x == 0)
    c_out[b] = (sbuf[0] + sbuf[1] + sbuf[2] + sbuf[3]) * (1.0f / 16129.0f);
}

// ---- fp32 -> fp16 streaming conversion body (RNE), grid-stride over n8 -----
__device__ __forceinline__ void wconv_body(const float* __restrict__ w,
                                           _Float16* __restrict__ wh,
                                           int start, int stride)
{
  const int n8 = 4096 * 4096 / 8;
  const float4* w4 = (const float4*)w;
  for (int i = start; i < n8; i += stride) {
    const float4 a = w4[2 * i];
    const float4 b = w4[2 * i + 1];
    halfx8 h = { (_Float16)a.x, (_Float16)a.y, (_Float16)a.z, (_Float16)a.w,
                 (_Float16)b.x, (_Float16)b.y, (_Float16)b.z, (_Float16)b.w };
    ((halfx8*)wh)[i] = h;
  }
}

// ---- attention (wave 0, exact) + layer 1 fused; extra blocks do wconv ------
__global__ __launch_bounds__(256) void attn_l1w_kernel(
    const float* __restrict__ c, const float* __restrict__ rot,
    const float* __restrict__ ent, const float* __restrict__ W1,
    const float* __restrict__ b1, float* __restrict__ act1,
    _Float16* __restrict__ a1h,
    const float* __restrict__ wsrc, _Float16* __restrict__ wdst)
{
  if (blockIdx.x >= 512) {  // wconv role: 2048 blocks
    wconv_body(wsrc, wdst, (blockIdx.x - 512) * 256 + threadIdx.x, 2048 * 256);
    return;
  }
  __shared__ float sattn;
  const int i = blockIdx.x;
  if (threadIdx.x < 64) {
    const int lane = threadIdx.x;
    const float t = rot[0] * ent[0] * c[i];
    float vals[8], cj[8];
    float mx = -1e30f;
    #pragma unroll
    for (int u = 0; u < 8; ++u) {
      float cv = c[lane + u * 64];
      cj[u] = cv;
      vals[u] = t * cv;
      mx = fmaxf(mx, vals[u]);
    }
    #pragma unroll
    for (int off = 32; off > 0; off >>= 1) mx = fmaxf(mx, __shfl_down(mx, off, 64));
    mx = __shfl(mx, 0, 64);
    float se = 0.f, sw = 0.f;
    #pragma unroll
    for (int u = 0; u < 8; ++u) {
      float e = __expf(vals[u] - mx);
      se += e;
      sw += e * cj[u];
    }
    #pragma unroll
    for (int off = 32; off > 0; off >>= 1) {
      se += __shfl_down(se, off, 64);
      sw += __shfl_down(sw, off, 64);
    }
    if (lane == 0) sattn = sw / se;
  }
  __syncthreads();
  const float av = sattn;
  #pragma unroll
  for (int k = 0; k < 16; ++k) {
    const int o = k * 256 + threadIdx.x;
    const float v = tanhf(av * W1[o] + b1[o]);
    act1[(size_t)i * 4096 + o] = v;
    a1h[(size_t)i * 4096 + o] = (_Float16)v;
  }
}

// ---------------- fp16-MFMA GEMM (R7 structure, both operands fp16) ---------
__global__ __launch_bounds__(256, 4) void gemm_kernel(
    const _Float16* __restrict__ A16, const _Float16* __restrict__ W16,
    float* __restrict__ part)
{
  __shared__ _Float16 As[2][BM][LDK];
  __shared__ _Float16 Ws[2][BN][LDK];
  const int K = 4096, N = 4096;
  const int tid  = threadIdx.x;
  const int lane = tid & 63;
  const int wave = tid >> 6;
  const int wm = (wave >> 1) * 64;
  const int wn = (wave & 1) * 64;
  const int q  = lane >> 4;
  const int ml = lane & 15;
  const int tileM = blockIdx.y * BM;
  const int tileN = blockIdx.x * BN;
  const int Kslice = K / gridDim.z;
  const int kbeg = blockIdx.z * Kslice;
  const int kend = kbeg + Kslice;
  float* Cb = part + (size_t)blockIdx.z * NEL;

  floatx4 acc[4][4] = {};

  const int r0  = tid >> 2;
  const int cc0 = (tid & 3) << 3;

  halfx8 pa[2], pw[2];
  auto load_tile = [&](int k0) {
    #pragma unroll
    for (int u = 0; u < 2; ++u) {
      pa[u] = *reinterpret_cast<const halfx8*>(
          A16 + (size_t)(tileM + r0 + u * 64) * K + k0 + cc0);
      pw[u] = *reinterpret_cast<const halfx8*>(
          W16 + (size_t)(tileN + r0 + u * 64) * K + k0 + cc0);
    }
  };
  auto store_tile = [&](int buf) {
    #pragma unroll
    for (int u = 0; u < 2; ++u) {
      *reinterpret_cast<halfx8*>(&As[buf][r0 + u * 64][cc0]) = pa[u];
      *reinterpret_cast<halfx8*>(&Ws[buf][r0 + u * 64][cc0]) = pw[u];
    }
  };

  load_tile(kbeg);
  store_tile(0);
  int cur = 0;

  for (int k0 = kbeg; k0 < kend; k0 += BK) {
    const bool more = (k0 + BK < kend);
    if (more) load_tile(k0 + BK);   // stays in flight across the raw barrier

    asm volatile("s_waitcnt lgkmcnt(0)" ::: "memory");
    __builtin_amdgcn_s_barrier();

    halfx8 af[4], bf[4];
    #pragma unroll
    for (int i = 0; i < 4; ++i)
      af[i] = *reinterpret_cast<const halfx8*>(&As[cur][wm + i * 16 + ml][q * 8]);
    #pragma unroll
    for (int j = 0; j < 4; ++j)
      bf[j] = *reinterpret_cast<const halfx8*>(&Ws[cur][wn + j * 16 + ml][q * 8]);

    #pragma unroll
    for (int i = 0; i < 4; ++i)
      #pragma unroll
      for (int j = 0; j < 4; ++j)
        acc[i][j] = __builtin_amdgcn_mfma_f32_16x16x32_f16(af[i], bf[j], acc[i][j], 0, 0, 0);

    if (more) store_tile(cur ^ 1);  // compiler's vmcnt wait lands here
    cur ^= 1;
  }

  // C/D layout: col=lane&15, row=(lane>>4)*4+reg
  #pragma unroll
  for (int i = 0; i < 4; ++i) {
    const int row0 = tileM + wm + i * 16 + q * 4;
    #pragma unroll
    for (int j = 0; j < 4; ++j) {
      const int col = tileN + wn + j * 16 + ml;
      #pragma unroll
      for (int r = 0; r < 4; ++r)
        Cb[(size_t)(row0 + r) * N + col] = acc[i][j][r];
    }
  }
}

// -- split-K combine + bias + tanh + fp16 copy; extra blocks wconv next W ----
template<int S>
__global__ __launch_bounds__(256) void combine_w_kernel(
    const float* __restrict__ part, const float* __restrict__ bias,
    float* __restrict__ outp, _Float16* __restrict__ houtp,
    const float* __restrict__ wsrc, _Float16* __restrict__ wdst)
{
  if (blockIdx.x >= 2048) {  // wconv role: 2048 blocks
    wconv_body(wsrc, wdst, (blockIdx.x - 2048) * 256 + threadIdx.x, 2048 * 256);
    return;
  }
  const int i4 = blockIdx.x * 256 + threadIdx.x;  // < NEL/4
  const floatx4* p4 = (const floatx4*)part;
  floatx4 s = p4[i4];
  #pragma unroll
  for (int z = 1; z < S; ++z) s += p4[(size_t)z * (NEL / 4) + i4];
  const floatx4 bv = ((const floatx4*)bias)[i4 & 1023];
  floatx4 o;
  #pragma unroll
  for (int r = 0; r < 4; ++r) o[r] = tanhf(s[r] + bv[r]);
  ((floatx4*)outp)[i4] = o;
  halfx4 h = { (_Float16)o[0], (_Float16)o[1], (_Float16)o[2], (_Float16)o[3] };
  ((halfx4*)houtp)[i4] = h;
}

// ---------------- final combine: sum S slices + bias + tanh -----------------
template<int S>
__global__ __launch_bounds__(256) void combine_tanh_kernel(
    const float* __restrict__ part, const float* __restrict__ bias,
    float* __restrict__ outp)
{
  const int i4 = blockIdx.x * 256 + threadIdx.x;  // < NEL/4
  const floatx4* p4 = (const floatx4*)part;
  floatx4 s = p4[i4];
  #pragma unroll
  for (int z = 1; z < S; ++z) s += p4[(size_t)z * (NEL / 4) + i4];
  const floatx4 bv = ((const floatx4*)bias)[i4 & 1023];
  floatx4 o;
  #pragma unroll
  for (int r = 0; r < 4; ++r) o[r] = tanhf(s[r] + bv[r]);
  ((floatx4*)outp)[i4] = o;
}

// ---------------- fid pairwise dots (low-contention, 256 blocks) ------------
__global__ __launch_bounds__(256) void fid_dots_kernel(
    const float* __restrict__ a1, const float* __restrict__ a2,
    const float* __restrict__ a3, const float* __restrict__ a4,
    float* __restrict__ D)
{
  __shared__ float sred[4][10];
  float s[10] = {0, 0, 0, 0, 0, 0, 0, 0, 0, 0};
  const int n4 = NEL / 4;
  const int stride = gridDim.x * blockDim.x;
  const floatx4* p1 = (const floatx4*)a1;
  const floatx4* p2 = (const floatx4*)a2;
  const floatx4* p3 = (const floatx4*)a3;
  const floatx4* p4 = (const floatx4*)a4;
  for (int i = blockIdx.x * 256 + threadIdx.x; i < n4; i += stride) {
    floatx4 v1 = p1[i], v2 = p2[i], v3 = p3[i], v4 = p4[i];
    #pragma unroll
    for (int r = 0; r < 4; ++r) {
      s[0] += v1[r] * v1[r]; s[1] += v1[r] * v2[r]; s[2] += v1[r] * v3[r];
      s[3] += v1[r] * v4[r]; s[4] += v2[r] * v2[r]; s[5] += v2[r] * v3[r];
      s[6] += v2[r] * v4[r]; s[7] += v3[r] * v3[r]; s[8] += v3[r] * v4[r];
      s[9] += v4[r] * v4[r];
    }
  }
  const int lane = threadIdx.x & 63, wv = threadIdx.x >> 6;
  #pragma unroll
  for (int p = 0; p < 10; ++p) {
    float v = s[p];
    #pragma unroll
    for (int off = 32; off > 0; off >>= 1) v += __shfl_down(v, off, 64);
    if (lane == 0) sred[wv][p] = v;
  }
  __syncthreads();
  if (threadIdx.x < 10) {
    float v = sred[0][threadIdx.x] + sred[1][threadIdx.x] +
              sred[2][threadIdx.x] + sred[3][threadIdx.x];
    atomicAdd(&D[threadIdx.x * 16], v);
  }
}

// ---------------- finalize graph weights ----------------
__global__ void finalize_kernel(const float* __restrict__ D, float* __restrict__ wout)
{
  const int i = threadIdx.x;
  if (i >= 16) return;
  const int p = i >> 2, qq = i & 3;
  const int a = p < qq ? p : qq;
  const int b = p < qq ? qq : p;
  const int base[4] = {0, 4, 7, 9};
  const float dpq = D[(base[a] + (b - a)) * 16];
  const float npv = sqrtf(D[base[p] * 16]) + 1e-12f;
  const float nqv = sqrtf(D[base[qq] * 16]) + 1e-12f;
  const float ch = dpq / (npv * nqv);
  const float fid = ch * ch;
  wout[i] = (fid >= 0.8f && p != qq) ? 1.0f : 0.0f;
}

extern "C" void kernel_launch(void* const* d_in, const int* in_sizes, int n_in,
                              void* d_out, int out_size, void* d_ws, size_t ws_size,
                              hipStream_t stream)
{
  const float* x   = (const float*)d_in[0];
  const float* cw  = (const float*)d_in[1];
  const float* cb  = (const float*)d_in[2];
  const float* rot = (const float*)d_in[3];
  const float* ent = (const float*)d_in[4];
  const float* W1  = (const float*)d_in[5];
  const float* b1  = (const float*)d_in[6];
  const float* W2  = (const float*)d_in[7];
  const float* b2  = (const float*)d_in[8];
  const float* W3  = (const float*)d_in[9];
  const float* b3  = (const float*)d_in[10];
  const float* W4  = (const float*)d_in[11];
  const float* b4  = (const float*)d_in[12];
  float* out = (float*)d_out;

  char*  ws    = (char*)d_ws;
  float* c_buf = (float*)(ws + 0);
  float* D     = (float*)(ws + 4096);
  float* act1  = (float*)(ws + 8192);
  float* act2  = act1 + NEL;
  float* act3  = act2 + NEL;
  _Float16* a1h = (_Float16*)(act3 + NEL);
  _Float16* a2h = a1h + NEL;
  _Float16* a3h = a2h + NEL;
  _Float16* wh  = a3h + NEL;                          // 4096x4096 fp16 = 32MB
  float* part  = (float*)(wh + (size_t)4096 * 4096);  // Z x NEL fp32 partials
  float* wout  = out + NEL;

  const size_t base_need = 8192 + (size_t)3 * NEL * 4 + (size_t)3 * NEL * 2
                         + (size_t)4096 * 4096 * 2;           // ~68 MB
  const bool sk8 = ws_size >= base_need + (size_t)8 * NEL * 4;  // ~132 MB

  conv_mean_kernel<<<512, 256, 0, stream>>>(x, cw, cb, c_buf, D);
  attn_l1w_kernel<<<2560, 256, 0, stream>>>(c_buf, rot, ent, W1, b1,
                                            act1, a1h, W2, wh);

  const int cgrid = NEL / 4 / 256;
  if (sk8) {
    dim3 g(32, 4, 8);  // 1024 blocks, 4 blocks/CU, single generation
    gemm_kernel<<<g, 256, 0, stream>>>(a1h, wh, part);
    combine_w_kernel<8><<<4096, 256, 0, stream>>>(part, b2, act2, a2h, W3, wh);
    gemm_kernel<<<g, 256, 0, stream>>>(a2h, wh, part);
    combine_w_kernel<8><<<4096, 256, 0, stream>>>(part, b3, act3, a3h, W4, wh);
    gemm_kernel<<<g, 256, 0, stream>>>(a3h, wh, part);
    combine_tanh_kernel<8><<<cgrid, 256, 0, stream>>>(part, b4, out);
  } else {
    dim3 g(32, 4, 4);  // 512 blocks; ~100MB footprint (R7-proven fallback)
    gemm_kernel<<<g, 256, 0, stream>>>(a1h, wh, part);
    combine_w_kernel<4><<<4096, 256, 0, stream>>>(part, b2, act2, a2h, W3, wh);
    gemm_kernel<<<g, 256, 0, stream>>>(a2h, wh, part);
    combine_w_kernel<4><<<4096, 256, 0, stream>>>(part, b3, act3, a3h, W4, wh);
    gemm_kernel<<<g, 256, 0, stream>>>(a3h, wh, part);
    combine_tanh_kernel<4><<<cgrid, 256, 0, stream>>>(part, b4, out);
  }

  fid_dots_kernel<<<256, 256, 0, stream>>>(act1, act2, act3, out, D);
  finalize_kernel<<<1, 64, 0, stream>>>(D, wout);
}